// Round 4
// baseline (627.789 us; speedup 1.0000x reference)
//
#include <hip/hip_runtime.h>
#include <hip/hip_bf16.h>
#include <hip/hip_cooperative_groups.h>

namespace cg = cooperative_groups;

// H=256, B=512 graphs, N=200000 nodes, 3 steps. One cooperative launch.
#define HID 256
#define NG 512
#define NBLK 256   // 1 block/CU -> cooperative co-residency unconditionally OK

__device__ __forceinline__ float sigmoidf_(float v) { return 1.f / (1.f + __expf(-v)); }

struct SM {
    float As[16][76];
    float Bs[16][76];
    float ql[HID];
    float red[4][HID];
    float mw[4], lw[4];
};

// ---------------------------------------------------------------------------
// C-tile[64x64] at (m0,n0) of A[MxK-slice] * B[NxK-slice]^T -> C (no bias)
__device__ __forceinline__ void gemm_tile(
    const float* __restrict__ A, int lda, const float* __restrict__ B, int ldb,
    float* __restrict__ C, int ldc, int m0, int n0, int kb, int KS,
    SM& sm, int tid)
{
    const int tx = tid & 15, ty = tid >> 4;
    const int r = tid >> 2, kc = (tid & 3) << 2;
    float acc[4][4] = {};
    const float* Ap = &A[(size_t)(m0 + r) * lda + kb + kc];
    const float* Bp = &B[(size_t)(n0 + r) * ldb + kb + kc];
    float4 av = *(const float4*)Ap;
    float4 bv = *(const float4*)Bp;
    for (int k0 = 0; k0 < KS; k0 += 16) {
        sm.As[kc + 0][r] = av.x; sm.As[kc + 1][r] = av.y;
        sm.As[kc + 2][r] = av.z; sm.As[kc + 3][r] = av.w;
        sm.Bs[kc + 0][r] = bv.x; sm.Bs[kc + 1][r] = bv.y;
        sm.Bs[kc + 2][r] = bv.z; sm.Bs[kc + 3][r] = bv.w;
        __syncthreads();
        if (k0 + 16 < KS) {
            av = *(const float4*)(Ap + k0 + 16);
            bv = *(const float4*)(Bp + k0 + 16);
        }
        #pragma unroll
        for (int kk = 0; kk < 16; ++kk) {
            float4 a  = *(const float4*)&sm.As[kk][ty << 2];
            float4 b4 = *(const float4*)&sm.Bs[kk][tx << 2];
            acc[0][0] += a.x * b4.x; acc[0][1] += a.x * b4.y; acc[0][2] += a.x * b4.z; acc[0][3] += a.x * b4.w;
            acc[1][0] += a.y * b4.x; acc[1][1] += a.y * b4.y; acc[1][2] += a.y * b4.z; acc[1][3] += a.y * b4.w;
            acc[2][0] += a.z * b4.x; acc[2][1] += a.z * b4.y; acc[2][2] += a.z * b4.z; acc[2][3] += a.z * b4.w;
            acc[3][0] += a.w * b4.x; acc[3][1] += a.w * b4.y; acc[3][2] += a.w * b4.z; acc[3][3] += a.w * b4.w;
        }
        __syncthreads();
    }
    #pragma unroll
    for (int i = 0; i < 4; ++i) {
        float4 o = make_float4(acc[i][0], acc[i][1], acc[i][2], acc[i][3]);
        *(float4*)&C[(size_t)(m0 + ty * 4 + i) * ldc + n0 + (tx << 2)] = o;
    }
}

// ---------------------------------------------------------------------------
// LSTM cell + attention (barrier-free online softmax, R3 structure) for one
// graph. cstate: per-thread LSTM c, lives in registers across steps.
__device__ void attn_graph(
    const float* __restrict__ x, const int* __restrict__ starts,
    const float* __restrict__ gp, const float* __restrict__ bcat,
    float* __restrict__ qs, float& cstate,
    int g, int tid, int step0, SM& sm)
{
    // ---- LSTM (gate order i,f,g,o); gates = gp0 + gp1 + bcat
    float ig, fg, gg, og;
    if (step0) {
        ig = bcat[tid]; fg = bcat[256 + tid]; gg = bcat[512 + tid]; og = bcat[768 + tid];
    } else {
        const float* a0 = gp + (size_t)g * 1024;
        const float* a1 = a0 + (size_t)512 * 1024;
        ig = a0[tid]       + a1[tid]       + bcat[tid];
        fg = a0[256 + tid] + a1[256 + tid] + bcat[256 + tid];
        gg = a0[512 + tid] + a1[512 + tid] + bcat[512 + tid];
        og = a0[768 + tid] + a1[768 + tid] + bcat[768 + tid];
    }
    float cp = step0 ? 0.f : cstate;
    float cn = sigmoidf_(fg) * cp + sigmoidf_(ig) * tanhf(gg);
    float h  = sigmoidf_(og) * tanhf(cn);
    cstate = cn;
    qs[(size_t)g * 512 + tid] = h;       // q_star[:, :256] = hs
    sm.ql[tid] = h;

    const int s0 = starts[g];
    const int nn = starts[g + 1] - s0;
    __syncthreads();

    float rout = 0.f;
    if (nn > 0) {
        const int w = tid >> 6, lane = tid & 63;
        const int j = lane >> 3;      // row within 8-row chunk
        const int s = lane & 7;       // 16B column-group within row

        float4 qf[8];
        #pragma unroll
        for (int k = 0; k < 8; ++k) qf[k] = *(const float4*)&sm.ql[k * 32 + s * 4];

        const int nch = (nn + 7) >> 3;
        const int last = s0 + nn - 1;
        const float NEG = -3.402823466e38f;

        float m_run = NEG, l_run = 0.f;
        float4 racc[8] = {};
        float4 xc[8], xn[8];

        int c = w;
        if (c < nch) {
            int node = s0 + c * 8 + j; if (node > last) node = last;
            const float* bp = x + (size_t)node * HID + s * 4;
            #pragma unroll
            for (int k = 0; k < 8; ++k) xc[k] = *(const float4*)(bp + k * 32);
        }
        for (; c < nch; c += 4) {
            if (c + 4 < nch) {
                int node = s0 + (c + 4) * 8 + j; if (node > last) node = last;
                const float* bp = x + (size_t)node * HID + s * 4;
                #pragma unroll
                for (int k = 0; k < 8; ++k) xn[k] = *(const float4*)(bp + k * 32);
            }
            const bool valid = (c * 8 + j) < nn;

            float e = 0.f;
            #pragma unroll
            for (int k = 0; k < 8; ++k)
                e += xc[k].x * qf[k].x + xc[k].y * qf[k].y + xc[k].z * qf[k].z + xc[k].w * qf[k].w;
            e += __shfl_xor(e, 1); e += __shfl_xor(e, 2); e += __shfl_xor(e, 4);
            e = valid ? e : NEG;

            float mc = e;
            mc = fmaxf(mc, __shfl_xor(mc, 8));
            mc = fmaxf(mc, __shfl_xor(mc, 16));
            mc = fmaxf(mc, __shfl_xor(mc, 32));
            float m_new = fmaxf(m_run, mc);
            float alpha = __expf(m_run - m_new);
            float p = valid ? __expf(e - m_new) : 0.f;
            float ps = p;
            ps += __shfl_xor(ps, 8); ps += __shfl_xor(ps, 16); ps += __shfl_xor(ps, 32);
            l_run = l_run * alpha + ps;
            m_run = m_new;
            #pragma unroll
            for (int k = 0; k < 8; ++k) {
                racc[k].x = racc[k].x * alpha + p * xc[k].x;
                racc[k].y = racc[k].y * alpha + p * xc[k].y;
                racc[k].z = racc[k].z * alpha + p * xc[k].z;
                racc[k].w = racc[k].w * alpha + p * xc[k].w;
            }
            #pragma unroll
            for (int k = 0; k < 8; ++k) xc[k] = xn[k];
        }

        // fold racc across the 8 row-slots (lane bits 3..5)
        #pragma unroll
        for (int k = 0; k < 8; ++k) {
            racc[k].x += __shfl_xor(racc[k].x, 8);  racc[k].y += __shfl_xor(racc[k].y, 8);
            racc[k].z += __shfl_xor(racc[k].z, 8);  racc[k].w += __shfl_xor(racc[k].w, 8);
            racc[k].x += __shfl_xor(racc[k].x, 16); racc[k].y += __shfl_xor(racc[k].y, 16);
            racc[k].z += __shfl_xor(racc[k].z, 16); racc[k].w += __shfl_xor(racc[k].w, 16);
            racc[k].x += __shfl_xor(racc[k].x, 32); racc[k].y += __shfl_xor(racc[k].y, 32);
            racc[k].z += __shfl_xor(racc[k].z, 32); racc[k].w += __shfl_xor(racc[k].w, 32);
        }
        if (j == 0) {
            #pragma unroll
            for (int k = 0; k < 8; ++k) *(float4*)&sm.red[w][k * 32 + s * 4] = racc[k];
            if (s == 0) { sm.mw[w] = m_run; sm.lw[w] = l_run; }
        }
        __syncthreads();

        float M = fmaxf(fmaxf(sm.mw[0], sm.mw[1]), fmaxf(sm.mw[2], sm.mw[3]));
        float f0 = __expf(sm.mw[0] - M), f1 = __expf(sm.mw[1] - M);
        float f2 = __expf(sm.mw[2] - M), f3 = __expf(sm.mw[3] - M);
        float L = sm.lw[0] * f0 + sm.lw[1] * f1 + sm.lw[2] * f2 + sm.lw[3] * f3;
        float r = sm.red[0][tid] * f0 + sm.red[1][tid] * f1
                + sm.red[2][tid] * f2 + sm.red[3][tid] * f3;
        rout = r / L;
    }
    qs[(size_t)g * 512 + HID + tid] = rout;   // q_star[:, 256:512] = r
    __syncthreads();                          // before sm reuse
}

// ---------------------------------------------------------------------------
__global__ __launch_bounds__(256) void fused_kernel(
    const float* __restrict__ x, const int* __restrict__ batch,
    const float* __restrict__ W_ih, const float* __restrict__ W_hh,
    const float* __restrict__ b_ih, const float* __restrict__ b_hh,
    const float* __restrict__ W_out, const float* __restrict__ b_out,
    float* __restrict__ out, int n, char* __restrict__ ws)
{
    __shared__ SM sm;
    float* qs     = (float*)(ws);                 // [512][512]
    float* gp     = (float*)(ws + 0x100000);      // [2][512][1024] split-K2 gates
    float* Wcat   = (float*)(ws + 0x500000);      // [1024][512]
    float* bcat   = (float*)(ws + 0x700000);      // [1024]
    int*   starts = (int*)  (ws + 0x701000);      // [513]
    float* op     = (float*)(ws + 0x710000);      // [4][512][256] out partials

    cg::grid_group grid = cg::this_grid();
    const int b = blockIdx.x, tid = threadIdx.x;
    const int gtid = b * 256 + tid;

    // ---- Phase A: Wcat = W_ih (+W_hh on k<256), bcat, starts (single scan)
    #pragma unroll
    for (int t = 0; t < 2; ++t) {
        int o = (gtid * 2 + t) * 4;               // float4-aligned, 0..524284
        int k = o & 511, row = o >> 9;
        float4 v = *(const float4*)&W_ih[o];
        if (k < 256) {
            float4 u = *(const float4*)&W_hh[row * 256 + k];
            v.x += u.x; v.y += u.y; v.z += u.z; v.w += u.w;
        }
        *(float4*)&Wcat[o] = v;
    }
    if (gtid < 1024) bcat[gtid] = b_ih[gtid] + b_hh[gtid];
    for (int i = gtid; i < n; i += NBLK * 256) {
        int b1 = batch[i];
        int b0 = (i == 0) ? -1 : batch[i - 1];
        for (int g2 = b0 + 1; g2 <= b1; ++g2) starts[g2] = i;
        if (i == n - 1) for (int g2 = b1 + 1; g2 <= NG; ++g2) starts[g2] = n;
    }
    grid.sync();

    float c0 = 0.f, c1 = 0.f;                     // LSTM cell state in registers
    for (int step = 0; step < 3; ++step) {
        if (step > 0) {
            // gates partials: gp[z] = qs[512x512] @ Wcat[:, zK]^T, z = b>>7
            int bz = b >> 7, by = (b >> 4) & 7, bx = b & 15;
            gemm_tile(qs, 512, Wcat, 512, gp + (size_t)bz * 512 * 1024, 1024,
                      by * 64, bx * 64, bz * 256, 256, sm, tid);
            grid.sync();
        }
        attn_graph(x, starts, gp, bcat, qs, c0, 2 * b,     tid, step == 0, sm);
        attn_graph(x, starts, gp, bcat, qs, c1, 2 * b + 1, tid, step == 0, sm);
        grid.sync();
    }

    // ---- out = qs @ W_out^T + b_out (split-K4 on 128 blocks, then reduce)
    if (b < 128) {
        int bz = b >> 5, by = (b >> 2) & 7, bx = b & 3;
        gemm_tile(qs, 512, W_out, 512, op + (size_t)bz * 512 * 256, 256,
                  by * 64, bx * 64, bz * 128, 128, sm, tid);
    }
    grid.sync();
    {
        int i0 = gtid, i1 = gtid + 65536;
        out[i0] = op[i0] + op[131072 + i0] + op[262144 + i0] + op[393216 + i0] + b_out[i0 & 255];
        out[i1] = op[i1] + op[131072 + i1] + op[262144 + i1] + op[393216 + i1] + b_out[i1 & 255];
    }
}

// ---------------------------------------------------------------------------
extern "C" void kernel_launch(void* const* d_in, const int* in_sizes, int n_in,
                              void* d_out, int out_size, void* d_ws, size_t ws_size,
                              hipStream_t stream)
{
    const float* x     = (const float*)d_in[0];
    const int*   batch = (const int*)d_in[1];
    const float* W_ih  = (const float*)d_in[2];
    const float* W_hh  = (const float*)d_in[3];
    const float* b_ih  = (const float*)d_in[4];
    const float* b_hh  = (const float*)d_in[5];
    const float* W_out = (const float*)d_in[6];
    const float* b_out = (const float*)d_in[7];
    float* out = (float*)d_out;
    int n = in_sizes[1];
    char* ws = (char*)d_ws;
    (void)n_in; (void)out_size; (void)ws_size;

    void* args[] = { (void*)&x, (void*)&batch, (void*)&W_ih, (void*)&W_hh,
                     (void*)&b_ih, (void*)&b_hh, (void*)&W_out, (void*)&b_out,
                     (void*)&out, (void*)&n, (void*)&ws };
    hipLaunchCooperativeKernel((const void*)fused_kernel, dim3(NBLK), dim3(256),
                               args, 0, stream);
}

// Round 5
// 455.093 us; speedup vs baseline: 1.3795x; 1.3795x over previous
//
#include <hip/hip_runtime.h>
#include <hip/hip_bf16.h>

// H=256, B=512 graphs, N=200000 nodes, 3 steps.
#define HID 256
#define NG 512

__device__ __forceinline__ float sigmoidf_(float v) { return 1.f / (1.f + __expf(-v)); }

// ---------------------------------------------------------------------------
// Wcat = W_ih (+W_hh on k<256); bcat = b_ih+b_hh; starts via binary search.
__global__ __launch_bounds__(256) void prep_kernel(
    const float* __restrict__ W_ih, const float* __restrict__ W_hh,
    const float* __restrict__ b_ih, const float* __restrict__ b_hh,
    const int* __restrict__ batch, int n,
    float* __restrict__ Wcat, float* __restrict__ bcat, int* __restrict__ starts)
{
    int b = blockIdx.x, tid = threadIdx.x;
    if (b < 512) {                                   // 512*256*4 = 524288 floats
        int o = (b * 256 + tid) * 4;
        int k = o & 511, row = o >> 9;
        float4 v = *(const float4*)&W_ih[o];
        if (k < 256) {
            float4 u = *(const float4*)&W_hh[row * 256 + k];
            v.x += u.x; v.y += u.y; v.z += u.z; v.w += u.w;
        }
        *(float4*)&Wcat[o] = v;
    } else if (b < 516) {
        int i = (b - 512) * 256 + tid;               // 0..1023
        bcat[i] = b_ih[i] + b_hh[i];
    } else {
        int g = (b - 516) * 256 + tid;               // 0..768 covers 513
        if (g > NG) return;
        if (g == NG) { starts[NG] = n; return; }
        int lo = 0, hi = n;
        while (lo < hi) {
            int mid = (lo + hi) >> 1;
            if (batch[mid] < g) lo = mid + 1; else hi = mid;
        }
        starts[g] = lo;
    }
}

// ---------------------------------------------------------------------------
// Fused LSTM cell + attention + readout; one block per graph; 512 blocks.
// Per-lane online softmax (no cross-lane m/l in the loop), prefetch depth 2.
__global__ __launch_bounds__(256, 2) void attn_kernel(
    const float* __restrict__ x, const int* __restrict__ starts,
    const float* __restrict__ gp, const float* __restrict__ bcat,
    float* __restrict__ cs, float* __restrict__ qs, int step0)
{
    __shared__ __align__(16) float ql[HID];
    __shared__ __align__(16) float red[4][HID];
    __shared__ float mw[4], lw[4];

    const int g = blockIdx.x;
    const int tid = threadIdx.x;

    // ---- LSTM (gate order i,f,g,o); gates = gp0 + gp1 + bcat
    float ig, fg, gg, og;
    if (step0) {
        ig = bcat[tid]; fg = bcat[256 + tid]; gg = bcat[512 + tid]; og = bcat[768 + tid];
    } else {
        const float* a0 = gp + (size_t)g * 1024;
        const float* a1 = a0 + (size_t)512 * 1024;
        ig = a0[tid]       + a1[tid]       + bcat[tid];
        fg = a0[256 + tid] + a1[256 + tid] + bcat[256 + tid];
        gg = a0[512 + tid] + a1[512 + tid] + bcat[512 + tid];
        og = a0[768 + tid] + a1[768 + tid] + bcat[768 + tid];
    }
    float cp = step0 ? 0.f : cs[g * HID + tid];
    float cn = sigmoidf_(fg) * cp + sigmoidf_(ig) * tanhf(gg);
    float h  = sigmoidf_(og) * tanhf(cn);
    cs[g * HID + tid] = cn;
    qs[(size_t)g * 512 + tid] = h;       // q_star[:, :256] = hs
    ql[tid] = h;

    const int s0 = starts[g];
    const int nn = starts[g + 1] - s0;
    if (nn <= 0) { qs[(size_t)g * 512 + HID + tid] = 0.f; return; }
    __syncthreads();

    const int w = tid >> 6, lane = tid & 63;
    const int j = lane >> 3;       // row-slot within 8-row chunk
    const int s = lane & 7;        // 16B column-group within row

    float4 qf[8];
    #pragma unroll
    for (int k = 0; k < 8; ++k) qf[k] = *(const float4*)&ql[k * 32 + s * 4];

    const int nch = (nn + 7) >> 3;
    const int last = s0 + nn - 1;
    const float NEG = -3.402823466e38f;

    float m_run = NEG, l_run = 0.f;
    float4 racc[8] = {};
    float4 xA[8], xB[8];

    // prologue: prefetch chunks w and w+4
    if (w < nch) {
        int node = s0 + w * 8 + j; if (node > last) node = last;
        const float* bp = x + (size_t)node * HID + s * 4;
        #pragma unroll
        for (int k = 0; k < 8; ++k) xA[k] = *(const float4*)(bp + k * 32);
    }
    if (w + 4 < nch) {
        int node = s0 + (w + 4) * 8 + j; if (node > last) node = last;
        const float* bp = x + (size_t)node * HID + s * 4;
        #pragma unroll
        for (int k = 0; k < 8; ++k) xB[k] = *(const float4*)(bp + k * 32);
    }

    #define PROCESS(XB, CC)                                                   \
    {                                                                         \
        const bool valid = ((CC) * 8 + j) < nn;                               \
        float e = 0.f;                                                        \
        _Pragma("unroll")                                                     \
        for (int k = 0; k < 8; ++k)                                           \
            e += XB[k].x * qf[k].x + XB[k].y * qf[k].y                        \
               + XB[k].z * qf[k].z + XB[k].w * qf[k].w;                       \
        e += __shfl_xor(e, 1); e += __shfl_xor(e, 2); e += __shfl_xor(e, 4);  \
        e = valid ? e : NEG;                                                  \
        float m_new = fmaxf(m_run, e);                                        \
        float alpha = __expf(m_run - m_new);                                  \
        float p = valid ? __expf(e - m_new) : 0.f;                            \
        l_run = l_run * alpha + p;                                            \
        m_run = m_new;                                                        \
        _Pragma("unroll")                                                     \
        for (int k = 0; k < 8; ++k) {                                         \
            racc[k].x = racc[k].x * alpha + p * XB[k].x;                      \
            racc[k].y = racc[k].y * alpha + p * XB[k].y;                      \
            racc[k].z = racc[k].z * alpha + p * XB[k].z;                      \
            racc[k].w = racc[k].w * alpha + p * XB[k].w;                      \
        }                                                                     \
    }

    int c = w;
    for (; c + 4 < nch; c += 8) {
        {   // chunk c from xA; refill xA <- c+8 (issued before compute)
            float4 xn[8];
            if (c + 8 < nch) {
                int node = s0 + (c + 8) * 8 + j; if (node > last) node = last;
                const float* bp = x + (size_t)node * HID + s * 4;
                #pragma unroll
                for (int k = 0; k < 8; ++k) xn[k] = *(const float4*)(bp + k * 32);
            }
            PROCESS(xA, c);
            #pragma unroll
            for (int k = 0; k < 8; ++k) xA[k] = xn[k];
        }
        {   // chunk c+4 from xB; refill xB <- c+12
            float4 xn[8];
            if (c + 12 < nch) {
                int node = s0 + (c + 12) * 8 + j; if (node > last) node = last;
                const float* bp = x + (size_t)node * HID + s * 4;
                #pragma unroll
                for (int k = 0; k < 8; ++k) xn[k] = *(const float4*)(bp + k * 32);
            }
            PROCESS(xB, c + 4);
            #pragma unroll
            for (int k = 0; k < 8; ++k) xB[k] = xn[k];
        }
    }
    if (c < nch) PROCESS(xA, c);
    #undef PROCESS

    // merge the 8 per-lane row-slot states within the wave (lane bits 3..5)
    #pragma unroll
    for (int bit = 8; bit <= 32; bit <<= 1) {
        float m2 = __shfl_xor(m_run, bit);
        float l2 = __shfl_xor(l_run, bit);
        float M  = fmaxf(m_run, m2);
        float a1 = __expf(m_run - M), a2 = __expf(m2 - M);
        l_run = l_run * a1 + l2 * a2;
        #pragma unroll
        for (int k = 0; k < 8; ++k) {
            racc[k].x = racc[k].x * a1 + __shfl_xor(racc[k].x, bit) * a2;
            racc[k].y = racc[k].y * a1 + __shfl_xor(racc[k].y, bit) * a2;
            racc[k].z = racc[k].z * a1 + __shfl_xor(racc[k].z, bit) * a2;
            racc[k].w = racc[k].w * a1 + __shfl_xor(racc[k].w, bit) * a2;
        }
        m_run = M;
    }
    if (j == 0) {
        #pragma unroll
        for (int k = 0; k < 8; ++k) *(float4*)&red[w][k * 32 + s * 4] = racc[k];
        if (s == 0) { mw[w] = m_run; lw[w] = l_run; }
    }
    __syncthreads();

    // merge the 4 wave-states (empty wave: m=NEG -> factor 0)
    float M = fmaxf(fmaxf(mw[0], mw[1]), fmaxf(mw[2], mw[3]));
    float f0 = __expf(mw[0] - M), f1 = __expf(mw[1] - M);
    float f2 = __expf(mw[2] - M), f3 = __expf(mw[3] - M);
    float L = lw[0] * f0 + lw[1] * f1 + lw[2] * f2 + lw[3] * f3;
    float r = red[0][tid] * f0 + red[1][tid] * f1 + red[2][tid] * f2 + red[3][tid] * f3;
    qs[(size_t)g * 512 + HID + tid] = r / L;     // q_star[:, 256:512] = r
}

// ---------------------------------------------------------------------------
// Cp[z][M x N] = A[M x K-slice] * B[N x K-slice]^T ; 64x64 tile, 4x4 micro.
__global__ __launch_bounds__(256) void gemm_splitk(
    const float* __restrict__ A, int lda,
    const float* __restrict__ B, int ldb,
    float* __restrict__ Cp, int ldc, int KS, size_t slice_stride)
{
    __shared__ float As[16][76];
    __shared__ float Bs[16][76];
    const int tid = threadIdx.x;
    const int tx = tid & 15, ty = tid >> 4;
    const int m0 = blockIdx.y * 64, n0 = blockIdx.x * 64;
    const int kb = blockIdx.z * KS;
    const int r = tid >> 2, kc = (tid & 3) << 2;
    float acc[4][4] = {};

    const float* Ap = &A[(size_t)(m0 + r) * lda + kb + kc];
    const float* Bp = &B[(size_t)(n0 + r) * ldb + kb + kc];
    float4 av = *(const float4*)Ap;
    float4 bv = *(const float4*)Bp;

    for (int k0 = 0; k0 < KS; k0 += 16) {
        As[kc + 0][r] = av.x; As[kc + 1][r] = av.y; As[kc + 2][r] = av.z; As[kc + 3][r] = av.w;
        Bs[kc + 0][r] = bv.x; Bs[kc + 1][r] = bv.y; Bs[kc + 2][r] = bv.z; Bs[kc + 3][r] = bv.w;
        __syncthreads();
        if (k0 + 16 < KS) {
            av = *(const float4*)(Ap + k0 + 16);
            bv = *(const float4*)(Bp + k0 + 16);
        }
        #pragma unroll
        for (int kk = 0; kk < 16; ++kk) {
            float4 a = *(const float4*)&As[kk][ty << 2];
            float4 b = *(const float4*)&Bs[kk][tx << 2];
            acc[0][0] += a.x * b.x; acc[0][1] += a.x * b.y; acc[0][2] += a.x * b.z; acc[0][3] += a.x * b.w;
            acc[1][0] += a.y * b.x; acc[1][1] += a.y * b.y; acc[1][2] += a.y * b.z; acc[1][3] += a.y * b.w;
            acc[2][0] += a.z * b.x; acc[2][1] += a.z * b.y; acc[2][2] += a.z * b.z; acc[2][3] += a.z * b.w;
            acc[3][0] += a.w * b.x; acc[3][1] += a.w * b.y; acc[3][2] += a.w * b.z; acc[3][3] += a.w * b.w;
        }
        __syncthreads();
    }
    float* out = Cp + blockIdx.z * slice_stride;
    #pragma unroll
    for (int i = 0; i < 4; ++i) {
        float4 o = make_float4(acc[i][0], acc[i][1], acc[i][2], acc[i][3]);
        *(float4*)&out[(size_t)(m0 + ty * 4 + i) * ldc + n0 + (tx << 2)] = o;
    }
}

// ---------------------------------------------------------------------------
__global__ __launch_bounds__(256) void finalize_out(
    const float* __restrict__ op, const float* __restrict__ b_out,
    float* __restrict__ out)
{
    int i = blockIdx.x * 256 + threadIdx.x;
    if (i < 512 * 256) {
        out[i] = op[i] + op[131072 + i] + op[262144 + i] + op[393216 + i] + b_out[i & 255];
    }
}

// ---------------------------------------------------------------------------
extern "C" void kernel_launch(void* const* d_in, const int* in_sizes, int n_in,
                              void* d_out, int out_size, void* d_ws, size_t ws_size,
                              hipStream_t stream)
{
    const float* x     = (const float*)d_in[0];
    const int*   batch = (const int*)d_in[1];
    const float* W_ih  = (const float*)d_in[2];
    const float* W_hh  = (const float*)d_in[3];
    const float* b_ih  = (const float*)d_in[4];
    const float* b_hh  = (const float*)d_in[5];
    const float* W_out = (const float*)d_in[6];
    const float* b_out = (const float*)d_in[7];
    float* out = (float*)d_out;
    const int n = in_sizes[1];
    (void)n_in; (void)out_size; (void)ws_size;

    char* ws = (char*)d_ws;
    float* qs     = (float*)(ws);                 // [512][512]
    float* cs     = (float*)(ws + 0x100000);      // [512][256]
    float* gp     = (float*)(ws + 0x180000);      // [2][512][1024] gate partials
    float* Wcat   = (float*)(ws + 0x580000);      // [1024][512]
    float* bcat   = (float*)(ws + 0x780000);      // [1024]
    int*   starts = (int*)  (ws + 0x781000);      // [513]
    float* op     = (float*)(ws + 0x790000);      // [4][512][256]

    prep_kernel<<<519, 256, 0, stream>>>(W_ih, W_hh, b_ih, b_hh, batch, n,
                                         Wcat, bcat, starts);
    for (int step = 0; step < 3; ++step) {
        if (step > 0) {
            gemm_splitk<<<dim3(16, 8, 2), 256, 0, stream>>>(
                qs, 512, Wcat, 512, gp, 1024, 256, (size_t)512 * 1024);
        }
        attn_kernel<<<NG, 256, 0, stream>>>(x, starts, gp, bcat, cs, qs, step == 0);
    }
    gemm_splitk<<<dim3(4, 8, 4), 256, 0, stream>>>(
        qs, 512, W_out, 512, op, 256, 128, (size_t)512 * 256);
    finalize_out<<<512, 256, 0, stream>>>(op, b_out, out);
}

// Round 6
// 413.535 us; speedup vs baseline: 1.5181x; 1.1005x over previous
//
#include <hip/hip_runtime.h>
#include <hip/hip_bf16.h>

// H=256, B=512 graphs, N=200000 nodes, 3 steps.
#define HID 256
#define NG 512

__device__ __forceinline__ float sigmoidf_(float v) { return 1.f / (1.f + __expf(-v)); }

// ---------------------------------------------------------------------------
// Wcat = W_ih (+W_hh on k<256); bcat = b_ih+b_hh; starts via binary search.
__global__ __launch_bounds__(256) void prep_kernel(
    const float* __restrict__ W_ih, const float* __restrict__ W_hh,
    const float* __restrict__ b_ih, const float* __restrict__ b_hh,
    const int* __restrict__ batch, int n,
    float* __restrict__ Wcat, float* __restrict__ bcat, int* __restrict__ starts)
{
    int b = blockIdx.x, tid = threadIdx.x;
    if (b < 512) {
        int o = (b * 256 + tid) * 4;
        int k = o & 511, row = o >> 9;
        float4 v = *(const float4*)&W_ih[o];
        if (k < 256) {
            float4 u = *(const float4*)&W_hh[row * 256 + k];
            v.x += u.x; v.y += u.y; v.z += u.z; v.w += u.w;
        }
        *(float4*)&Wcat[o] = v;
    } else if (b < 516) {
        int i = (b - 512) * 256 + tid;
        bcat[i] = b_ih[i] + b_hh[i];
    } else {
        int g = (b - 516) * 256 + tid;
        if (g > NG) return;
        if (g == NG) { starts[NG] = n; return; }
        int lo = 0, hi = n;
        while (lo < hi) {
            int mid = (lo + hi) >> 1;
            if (batch[mid] < g) lo = mid + 1; else hi = mid;
        }
        starts[g] = lo;
    }
}

// ---------------------------------------------------------------------------
// Fused LSTM cell + attention + readout; one block per graph.
// Lane-contiguous full-row loads (1 wave64 float4 load = one 1KB row),
// 4 rows/batch, depth-1 prefetch, ~70 live VGPRs (no spill/remat).
__global__ __launch_bounds__(256) void attn_kernel(
    const float* __restrict__ x, const int* __restrict__ starts,
    const float* __restrict__ gp, const float* __restrict__ bcat,
    float* __restrict__ cs, float* __restrict__ qs, int step0)
{
    __shared__ __align__(16) float ql[HID];
    __shared__ __align__(16) float red[4][HID];
    __shared__ float mw[4], lw[4];

    const int g = blockIdx.x;
    const int tid = threadIdx.x;

    // ---- LSTM (gate order i,f,g,o); gates = gp0 + gp1 + bcat
    float ig, fg, gg, og;
    if (step0) {
        ig = bcat[tid]; fg = bcat[256 + tid]; gg = bcat[512 + tid]; og = bcat[768 + tid];
    } else {
        const float* a0 = gp + (size_t)g * 1024;
        const float* a1 = a0 + (size_t)512 * 1024;
        ig = a0[tid]       + a1[tid]       + bcat[tid];
        fg = a0[256 + tid] + a1[256 + tid] + bcat[256 + tid];
        gg = a0[512 + tid] + a1[512 + tid] + bcat[512 + tid];
        og = a0[768 + tid] + a1[768 + tid] + bcat[768 + tid];
    }
    float cp = step0 ? 0.f : cs[g * HID + tid];
    float cn = sigmoidf_(fg) * cp + sigmoidf_(ig) * tanhf(gg);
    float h  = sigmoidf_(og) * tanhf(cn);
    cs[g * HID + tid] = cn;
    qs[(size_t)g * 512 + tid] = h;       // q_star[:, :256] = hs
    ql[tid] = h;

    const int s0 = starts[g];
    const int nn = starts[g + 1] - s0;
    if (nn <= 0) { qs[(size_t)g * 512 + HID + tid] = 0.f; return; }
    __syncthreads();

    const int w = tid >> 6, lane = tid & 63;
    const float4 qv = *(const float4*)&ql[lane * 4];
    const float* xg = x + (size_t)s0 * HID + lane * 4;
    const int lastrow = nn - 1;
    const float NEG = -3.402823466e38f;

    float m_run = NEG, l_run = 0.f;
    float4 racc = make_float4(0.f, 0.f, 0.f, 0.f);
    float4 y0, y1, y2, y3, z0, z1, z2, z3;

    int row0 = 4 * w;                       // wave w owns row-groups ≡ w (mod 4)
    if (row0 < nn) {                        // prologue load (rows clamped)
        int r1 = row0 + 1 > lastrow ? lastrow : row0 + 1;
        int r2 = row0 + 2 > lastrow ? lastrow : row0 + 2;
        int r3 = row0 + 3 > lastrow ? lastrow : row0 + 3;
        y0 = *(const float4*)(xg + (size_t)row0 * HID);
        y1 = *(const float4*)(xg + (size_t)r1 * HID);
        y2 = *(const float4*)(xg + (size_t)r2 * HID);
        y3 = *(const float4*)(xg + (size_t)r3 * HID);
    }
    for (; row0 < nn; row0 += 16) {
        const int nr = row0 + 16;
        if (nr < nn) {                      // prefetch next batch
            int r1 = nr + 1 > lastrow ? lastrow : nr + 1;
            int r2 = nr + 2 > lastrow ? lastrow : nr + 2;
            int r3 = nr + 3 > lastrow ? lastrow : nr + 3;
            z0 = *(const float4*)(xg + (size_t)nr * HID);
            z1 = *(const float4*)(xg + (size_t)r1 * HID);
            z2 = *(const float4*)(xg + (size_t)r2 * HID);
            z3 = *(const float4*)(xg + (size_t)r3 * HID);
        }
        // 4 interleaved 64-lane dot reductions
        float d0 = y0.x * qv.x + y0.y * qv.y + y0.z * qv.z + y0.w * qv.w;
        float d1 = y1.x * qv.x + y1.y * qv.y + y1.z * qv.z + y1.w * qv.w;
        float d2 = y2.x * qv.x + y2.y * qv.y + y2.z * qv.z + y2.w * qv.w;
        float d3 = y3.x * qv.x + y3.y * qv.y + y3.z * qv.z + y3.w * qv.w;
        #pragma unroll
        for (int off = 1; off < 64; off <<= 1) {
            d0 += __shfl_xor(d0, off);
            d1 += __shfl_xor(d1, off);
            d2 += __shfl_xor(d2, off);
            d3 += __shfl_xor(d3, off);
        }
        const float e0 = d0;                                   // row0 < nn always
        const float e1 = (row0 + 1 < nn) ? d1 : NEG;
        const float e2 = (row0 + 2 < nn) ? d2 : NEG;
        const float e3 = (row0 + 3 < nn) ? d3 : NEG;
        const float em = fmaxf(fmaxf(e0, e1), fmaxf(e2, e3));
        if (em > m_run) {                   // wave-uniform branch
            const float alpha = __expf(m_run - em);            // 1st batch: 0
            const float p0 = __expf(e0 - em);
            const float p1 = __expf(e1 - em);                  // NEG -> 0
            const float p2 = __expf(e2 - em);
            const float p3 = __expf(e3 - em);
            l_run = l_run * alpha + (p0 + p1) + (p2 + p3);
            racc.x = racc.x * alpha + p0 * y0.x + p1 * y1.x + p2 * y2.x + p3 * y3.x;
            racc.y = racc.y * alpha + p0 * y0.y + p1 * y1.y + p2 * y2.y + p3 * y3.y;
            racc.z = racc.z * alpha + p0 * y0.z + p1 * y1.z + p2 * y2.z + p3 * y3.z;
            racc.w = racc.w * alpha + p0 * y0.w + p1 * y1.w + p2 * y2.w + p3 * y3.w;
            m_run = em;
        } else {                            // common fast path: no rescale
            const float p0 = __expf(e0 - m_run);
            const float p1 = __expf(e1 - m_run);
            const float p2 = __expf(e2 - m_run);
            const float p3 = __expf(e3 - m_run);
            l_run += (p0 + p1) + (p2 + p3);
            racc.x += p0 * y0.x + p1 * y1.x + p2 * y2.x + p3 * y3.x;
            racc.y += p0 * y0.y + p1 * y1.y + p2 * y2.y + p3 * y3.y;
            racc.z += p0 * y0.z + p1 * y1.z + p2 * y2.z + p3 * y3.z;
            racc.w += p0 * y0.w + p1 * y1.w + p2 * y2.w + p3 * y3.w;
        }
        y0 = z0; y1 = z1; y2 = z2; y3 = z3;
    }

    // merge the 4 wave states via LDS (wave with no rows: m=NEG -> factor 0)
    *(float4*)&red[w][lane * 4] = racc;
    if (lane == 0) { mw[w] = m_run; lw[w] = l_run; }
    __syncthreads();
    const float M = fmaxf(fmaxf(mw[0], mw[1]), fmaxf(mw[2], mw[3]));
    const float f0 = __expf(mw[0] - M), f1 = __expf(mw[1] - M);
    const float f2 = __expf(mw[2] - M), f3 = __expf(mw[3] - M);
    const float L = lw[0] * f0 + lw[1] * f1 + lw[2] * f2 + lw[3] * f3;
    const float r = red[0][tid] * f0 + red[1][tid] * f1
                  + red[2][tid] * f2 + red[3][tid] * f3;
    qs[(size_t)g * 512 + HID + tid] = r / L;     // q_star[:, 256:512] = r
}

// ---------------------------------------------------------------------------
// Cp[z][M x N] = A[M x K-slice] * B[N x K-slice]^T ; 64x64 tile, 4x4 micro.
__global__ __launch_bounds__(256) void gemm_splitk(
    const float* __restrict__ A, int lda,
    const float* __restrict__ B, int ldb,
    float* __restrict__ Cp, int ldc, int KS, size_t slice_stride)
{
    __shared__ float As[16][76];
    __shared__ float Bs[16][76];
    const int tid = threadIdx.x;
    const int tx = tid & 15, ty = tid >> 4;
    const int m0 = blockIdx.y * 64, n0 = blockIdx.x * 64;
    const int kb = blockIdx.z * KS;
    const int r = tid >> 2, kc = (tid & 3) << 2;
    float acc[4][4] = {};

    const float* Ap = &A[(size_t)(m0 + r) * lda + kb + kc];
    const float* Bp = &B[(size_t)(n0 + r) * ldb + kb + kc];
    float4 av = *(const float4*)Ap;
    float4 bv = *(const float4*)Bp;

    for (int k0 = 0; k0 < KS; k0 += 16) {
        As[kc + 0][r] = av.x; As[kc + 1][r] = av.y; As[kc + 2][r] = av.z; As[kc + 3][r] = av.w;
        Bs[kc + 0][r] = bv.x; Bs[kc + 1][r] = bv.y; Bs[kc + 2][r] = bv.z; Bs[kc + 3][r] = bv.w;
        __syncthreads();
        if (k0 + 16 < KS) {
            av = *(const float4*)(Ap + k0 + 16);
            bv = *(const float4*)(Bp + k0 + 16);
        }
        #pragma unroll
        for (int kk = 0; kk < 16; ++kk) {
            float4 a = *(const float4*)&As[kk][ty << 2];
            float4 b = *(const float4*)&Bs[kk][tx << 2];
            acc[0][0] += a.x * b.x; acc[0][1] += a.x * b.y; acc[0][2] += a.x * b.z; acc[0][3] += a.x * b.w;
            acc[1][0] += a.y * b.x; acc[1][1] += a.y * b.y; acc[1][2] += a.y * b.z; acc[1][3] += a.y * b.w;
            acc[2][0] += a.z * b.x; acc[2][1] += a.z * b.y; acc[2][2] += a.z * b.z; acc[2][3] += a.z * b.w;
            acc[3][0] += a.w * b.x; acc[3][1] += a.w * b.y; acc[3][2] += a.w * b.z; acc[3][3] += a.w * b.w;
        }
        __syncthreads();
    }
    float* out = Cp + blockIdx.z * slice_stride;
    #pragma unroll
    for (int i = 0; i < 4; ++i) {
        float4 o = make_float4(acc[i][0], acc[i][1], acc[i][2], acc[i][3]);
        *(float4*)&out[(size_t)(m0 + ty * 4 + i) * ldc + n0 + (tx << 2)] = o;
    }
}

// ---------------------------------------------------------------------------
__global__ __launch_bounds__(256) void finalize_out(
    const float* __restrict__ op, const float* __restrict__ b_out,
    float* __restrict__ out)
{
    int i = blockIdx.x * 256 + threadIdx.x;
    if (i < 512 * 256) {
        out[i] = op[i] + op[131072 + i] + op[262144 + i] + op[393216 + i] + b_out[i & 255];
    }
}

// ---------------------------------------------------------------------------
extern "C" void kernel_launch(void* const* d_in, const int* in_sizes, int n_in,
                              void* d_out, int out_size, void* d_ws, size_t ws_size,
                              hipStream_t stream)
{
    const float* x     = (const float*)d_in[0];
    const int*   batch = (const int*)d_in[1];
    const float* W_ih  = (const float*)d_in[2];
    const float* W_hh  = (const float*)d_in[3];
    const float* b_ih  = (const float*)d_in[4];
    const float* b_hh  = (const float*)d_in[5];
    const float* W_out = (const float*)d_in[6];
    const float* b_out = (const float*)d_in[7];
    float* out = (float*)d_out;
    const int n = in_sizes[1];
    (void)n_in; (void)out_size; (void)ws_size;

    char* ws = (char*)d_ws;
    float* qs     = (float*)(ws);                 // [512][512]
    float* cs     = (float*)(ws + 0x100000);      // [512][256]
    float* gp     = (float*)(ws + 0x180000);      // [2][512][1024] gate partials
    float* Wcat   = (float*)(ws + 0x580000);      // [1024][512]
    float* bcat   = (float*)(ws + 0x780000);      // [1024]
    int*   starts = (int*)  (ws + 0x781000);      // [513]
    float* op     = (float*)(ws + 0x790000);      // [4][512][256]

    prep_kernel<<<519, 256, 0, stream>>>(W_ih, W_hh, b_ih, b_hh, batch, n,
                                         Wcat, bcat, starts);
    for (int step = 0; step < 3; ++step) {
        if (step > 0) {
            gemm_splitk<<<dim3(16, 8, 2), 256, 0, stream>>>(
                qs, 512, Wcat, 512, gp, 1024, 256, (size_t)512 * 1024);
        }
        attn_kernel<<<NG, 256, 0, stream>>>(x, starts, gp, bcat, cs, qs, step == 0);
    }
    gemm_splitk<<<dim3(4, 8, 4), 256, 0, stream>>>(
        qs, 512, W_out, 512, op, 256, 128, (size_t)512 * 256);
    finalize_out<<<512, 256, 0, stream>>>(op, b_out, out);
}